// Round 4
// baseline (118395.325 us; speedup 1.0000x reference)
//
#include <hip/hip_runtime.h>

#define CC 56
#define TT 64
#define GRID 1024            // worker blocks (one row each); block GRID = master
#define NT 256
#define NFL 256              // flag lines
#define SS 32                // 128 B stride between sync lines
#define FB 32768             // flag base (int idx): 256 lines
#define AGENT __HIP_MEMORY_SCOPE_AGENT

// ---- ws byte offsets
#define OFF_FWS   204800     // dense carry vectors (fp32), after iws region (163840 B)
#define OFF_W1BF  262144     // W1 bf16, 2 MB
#define OFF_W2BF  2359296    // W2 bf16, 2 MB
#define OFF_PRIV  4456448    // 1024 x 32 KB private regions (self-local only!)
#define PRIVB     32768

// ---- private region offsets (ushort units) — written and read by the SAME block
#define PM2  0               // M2 rows (i,g,o) 3x1024 bf16
#define PM3  3072
#define PW1R 6144
#define PW2R 9216
#define PV2  12288
#define PV3  13312
#define PV1  14336
#define PA0  15360           // byte 30720: A0 fp32 3x56

// ---- fws float offsets (dense)
#define FS1   0
#define FS2   1024
#define FS3   2048
#define FTD1  3072           // parity slots 3072/4096
#define FTD2  5120           // parity slots 5120/6144
#define FRC1  7168           // 56

#define PGUARD (1 << 20)

static __device__ __forceinline__ float wredsum(float v) {
#pragma unroll
  for (int m = 32; m; m >>= 1) v += __shfl_xor(v, m, 64);
  return v;
}
static __device__ __forceinline__ float sigm(float x) { return 1.f / (1.f + __expf(-x)); }
static __device__ __forceinline__ float ftanh(float x) {
  x = fminf(15.f, fmaxf(-15.f, x));
  float e = __expf(2.f * x);
  return (e - 1.f) / (e + 1.f);
}

// coherent accessors (agent-scope) — only for cross-block rewritten data
static __device__ __forceinline__ float2 cld2(const float* p) {
  unsigned long long u = __hip_atomic_load((const unsigned long long*)p, __ATOMIC_RELAXED, AGENT);
  union { unsigned long long u; float2 f; } c; c.u = u; return c.f;
}
static __device__ __forceinline__ float4 cld4(const float* p) {
  float2 a = cld2(p), b = cld2(p + 2);
  return make_float4(a.x, a.y, b.x, b.y);
}
static __device__ __forceinline__ float cld1(const float* p) {
  return __uint_as_float(__hip_atomic_load((const unsigned int*)p, __ATOMIC_RELAXED, AGENT));
}
static __device__ __forceinline__ void cst1(float* p, float v) {
  __hip_atomic_store((unsigned int*)p, __float_as_uint(v), __ATOMIC_RELAXED, AGENT);
}
static __device__ __forceinline__ void cstu2(unsigned* p, unsigned a, unsigned b) {
  unsigned long long u = (unsigned long long)a | ((unsigned long long)b << 32);
  __hip_atomic_store((unsigned long long*)p, u, __ATOMIC_RELAXED, AGENT);
}
static __device__ __forceinline__ int ldi(const int* p) {
  return __hip_atomic_load(p, __ATOMIC_RELAXED, AGENT);
}
static __device__ __forceinline__ void sti(int* p, int v) {
  __hip_atomic_store(p, v, __ATOMIC_RELAXED, AGENT);
}
// release store: drains this wave's prior stores to the coherence point first
static __device__ __forceinline__ void relst(int* p, int v) {
  __hip_atomic_store(p, v, __ATOMIC_RELEASE, AGENT);
}

// bf16 pack (RNE) + dot helpers
static __device__ __forceinline__ unsigned bfp(float lo, float hi) {
  unsigned a = __float_as_uint(lo), b = __float_as_uint(hi);
  a = (a + 0x7fffu + ((a >> 16) & 1u)) >> 16;
  b = (b + 0x7fffu + ((b >> 16) & 1u)) >> 16;
  return a | (b << 16);
}
static __device__ __forceinline__ float blo(unsigned u) { return __uint_as_float(u << 16); }
static __device__ __forceinline__ float bhi(unsigned u) { return __uint_as_float(u & 0xffff0000u); }
static __device__ __forceinline__ float bdot4(uint4 w, float4 a, float4 b) {
  float r =  blo(w.x) * a.x;
  r = fmaf(bhi(w.x), a.y, r);
  r = fmaf(blo(w.y), a.z, r);
  r = fmaf(bhi(w.y), a.w, r);
  r = fmaf(blo(w.z), b.x, r);
  r = fmaf(bhi(w.z), b.y, r);
  r = fmaf(blo(w.w), b.z, r);
  r = fmaf(bhi(w.w), b.w, r);
  return r;
}
static __device__ __forceinline__ float asum4(float4 v) {
  return fabsf(v.x) + fabsf(v.y) + fabsf(v.z) + fabsf(v.w);
}

// full-wave 1024-dot: lane owns elements 16*lane..16*lane+15 (bf16 weights, plain loads)
#define DOT16(wp, qoff, A, B, C, D)                                   \
  ({ uint4 _qa = (wp)[(qoff) + 2 * lane];                             \
     uint4 _qb = (wp)[(qoff) + 2 * lane + 1];                         \
     wredsum(bdot4(_qa, A, B) + bdot4(_qb, C, D)); })

// solo-wave flag spin: lane0 polls, wave reconverges after the if
static __device__ __forceinline__ void sflag(const int* iws, int fl, int f) {
  if ((threadIdx.x & 63) == 0) {
    int gd = 0;
    while (ldi(iws + FB + SS * fl) < f) {
      __builtin_amdgcn_s_sleep(1);
      if (++gd > PGUARD) break;
    }
  }
  __asm__ __volatile__("" ::: "memory");
}

// 1024-dot: wave-local, 16 fp32/lane (prologue constants)
static __device__ __forceinline__ float dotw(const float* a, const float* c, int lane) {
  const float4* a4 = (const float4*)a;
  const float4* c4 = (const float4*)c;
  float acc = 0.f;
#pragma unroll
  for (int j = 0; j < 4; ++j) {
    float4 x = a4[lane * 4 + j], y = c4[lane * 4 + j];
    acc = fmaf(x.x, y.x, fmaf(x.y, y.y, fmaf(x.z, y.z, fmaf(x.w, y.w, acc))));
  }
  return wredsum(acc);
}

__global__ void __launch_bounds__(NT, 4) predcells(
    const float* __restrict__ inp,
    const float* __restrict__ W0w, const float* __restrict__ W0b,
    const float* __restrict__ W1w, const float* __restrict__ W1b,
    const float* __restrict__ W2w, const float* __restrict__ W2b,
    const float* __restrict__ Wi1, const float* __restrict__ b1,
    const float* __restrict__ Wi2, const float* __restrict__ b2,
    const float* __restrict__ Wi3, const float* __restrict__ b3,
    const float* __restrict__ V1w, const float* __restrict__ V1b,
    const float* __restrict__ V2w, const float* __restrict__ V2b,
    const float* __restrict__ V3w, const float* __restrict__ V3b,
    const int* __restrict__ itn,
    float* __restrict__ out, char* ws)
{
  const int tid = threadIdx.x;
  const int lane = tid & 63;
  const int wv = tid >> 6;
  const int b = blockIdx.x;

  int* iws = (int*)ws;
  float* fws = (float*)(ws + OFF_FWS);

  // ======== dedicated master block: pure poll + relay, v = 1..129
  if (b == GRID) {
    for (int v = 1; v <= 129; ++v) {
      int gd = 0;
      for (;;) {
        int a0 = ldi(iws + SS * tid);
        int a1 = ldi(iws + SS * (tid + 256));
        int a2 = ldi(iws + SS * (tid + 512));
        int a3 = ldi(iws + SS * (tid + 768));
        if (a0 >= v && a1 >= v && a2 >= v && a3 >= v) break;
        if (++gd > PGUARD) break;
      }
      __syncthreads();                       // all slots confirmed before any flag
      sti(iws + FB + SS * tid, v);           // 256 flag lines, 1 store each
    }
    return;
  }

  const bool hasV1 = (b < CC);
  const int fl = b & (NFL - 1);
  unsigned short* priv = (unsigned short*)(ws + OFF_PRIV + (size_t)b * PRIVB);
  unsigned short* w1bf = (unsigned short*)(ws + OFF_W1BF);
  unsigned short* w2bf = (unsigned short*)(ws + OFF_W2BF);

  __shared__ float arow[6][1024];            // GEMM staging (24 KB)
  __shared__ float psA[3];
  __shared__ float cs1[3], cs2[3], cs3[3];

  const int gofs = (wv == 0) ? 0 : ((wv == 1) ? 2048 : 3072);

  const float lam = (itn[0] <= 1000) ? 1e-4f : 1e-2f;
  const float lam2 = lam * lam;
  float l0 = 0.f, l1 = 0.f, l2 = 0.f;        // block-0 wave-0 registers

  // ======== phase 0: W1/W2 row b -> shared bf16 (agent stores, cross-block)
  {
    float4 r1 = ((const float4*)(W1w + (size_t)b * 1024))[tid];
    cstu2((unsigned*)(w1bf + (size_t)b * 1024 + 4 * tid), bfp(r1.x, r1.y), bfp(r1.z, r1.w));
    float4 r2 = ((const float4*)(W2w + (size_t)b * 1024))[tid];
    cstu2((unsigned*)(w2bf + (size_t)b * 1024 + 4 * tid), bfp(r2.x, r2.y), bfp(r2.z, r2.w));
  }
  __syncthreads();                           // drain all waves' stores
  if (tid == 0) sti(iws + SS * b, 1);        // arrive(1)

  // ======== phase 1 (overlaps barrier window): constants + private weights (PLAIN stores)
  if (wv < 3) {
    float c1v = b1[b + gofs] + dotw(Wi1 + (size_t)(b + gofs) * 2048, W0b, lane);
    float c2v = b2[b + gofs] + dotw(Wi2 + (size_t)(b + gofs) * 2048, W1b, lane);
    float c3v = b3[b + gofs] + dotw(Wi3 + (size_t)(b + gofs) * 1024, W2b, lane);
    if (lane == 0) { cs1[wv] = c1v; cs2[wv] = c2v; cs3[wv] = c3v; }
    if (lane < CC) {
      const float* wr = Wi1 + (size_t)(b + gofs) * 2048;
      float acc = 0.f;
      for (int k = 0; k < 1024; ++k) acc = fmaf(wr[k], W0w[k * CC + lane], acc);
      ((float*)(priv + PA0))[wv * CC + lane] = acc;
    }
    {
      float4 x = ((const float4*)(Wi1 + (size_t)(b + gofs) * 2048 + 1024))[lane];
      ((uint2*)(priv + PW1R + wv * 1024))[lane] = make_uint2(bfp(x.x, x.y), bfp(x.z, x.w));
      float4 y = ((const float4*)(Wi2 + (size_t)(b + gofs) * 2048 + 1024))[lane];
      ((uint2*)(priv + PW2R + wv * 1024))[lane] = make_uint2(bfp(y.x, y.y), bfp(y.z, y.w));
    }
  } else {
#pragma unroll
    for (int j = 0; j < 4; ++j) {
      int i = lane * 4 + j;
      float4 a = ((const float4*)(V2w + (size_t)b * 1024))[i];
      ((uint2*)(priv + PV2))[i] = make_uint2(bfp(a.x, a.y), bfp(a.z, a.w));
      float4 c = ((const float4*)(V3w + (size_t)b * 1024))[i];
      ((uint2*)(priv + PV3))[i] = make_uint2(bfp(c.x, c.y), bfp(c.z, c.w));
      if (hasV1) {
        float4 d = ((const float4*)(V1w + (size_t)b * 1024))[i];
        ((uint2*)(priv + PV1))[i] = make_uint2(bfp(d.x, d.y), bfp(d.z, d.w));
      }
    }
  }
  __syncthreads();
  // t=0 init: s1_0 = act(A0@x_0 + c1); publish S1/TD1_0 (certified at flag 2)
  if (wv < 3) {
    float p = 0.f, ax = 0.f;
    if (lane < CC) {
      float xv = inp[lane];
      p = ((const float*)(priv + PA0))[wv * CC + lane] * xv;
      ax = fabsf(xv);
    }
    p = wredsum(p);
    ax = wredsum(ax);
    if (lane == 0) psA[wv] = p;
    if (b == 0 && wv == 0) l0 += ax;         // |nTD0_0|
  }
  __syncthreads();
  if (tid == 0) {
    float s1v = sigm(psA[2] + cs1[2]) * ftanh(sigm(psA[0] + cs1[0]) * ftanh(psA[1] + cs1[1]));
    cst1(fws + FS1 + b, s1v);
    cst1(fws + FTD1 + b, s1v);               // parity 0
  }
  // wait flag 1 (w1bf/w2bf certified), 4-wave block path
  if (tid == 0) {
    int gd = 0;
    while (ldi(iws + FB + SS * fl) < 1) {
      __builtin_amdgcn_s_sleep(1);
      if (++gd > PGUARD) break;
    }
  }
  __asm__ __volatile__("" ::: "memory");
  __syncthreads();

  // ======== phase 2: GEMMs M2 = Wi2_L@W1, M3 = Wi3@W2 -> private bf16 (PLAIN)
  {
#pragma unroll
    for (int w = 0; w < 3; ++w) {
      int go = (w == 0) ? 0 : ((w == 1) ? 2048 : 3072);
      ((float4*)arow[w])[tid]     = ((const float4*)(Wi2 + (size_t)(b + go) * 2048))[tid];
      ((float4*)arow[3 + w])[tid] = ((const float4*)(Wi3 + (size_t)(b + go) * 1024))[tid];
    }
    __syncthreads();
    float ac[12];
#pragma unroll
    for (int j = 0; j < 12; ++j) ac[j] = 0.f;
    const uint2* wsrc = (const uint2*)w1bf;
#pragma unroll 4
    for (int k = 0; k < 1024; ++k) {
      uint2 wp = wsrc[k * 256 + tid];
      float f0 = blo(wp.x), f1 = bhi(wp.x), f2 = blo(wp.y), f3 = bhi(wp.y);
      float ai = arow[0][k], ag = arow[1][k], ao = arow[2][k];
      ac[0] = fmaf(ai, f0, ac[0]); ac[1] = fmaf(ai, f1, ac[1]); ac[2] = fmaf(ai, f2, ac[2]); ac[3] = fmaf(ai, f3, ac[3]);
      ac[4] = fmaf(ag, f0, ac[4]); ac[5] = fmaf(ag, f1, ac[5]); ac[6] = fmaf(ag, f2, ac[6]); ac[7] = fmaf(ag, f3, ac[7]);
      ac[8] = fmaf(ao, f0, ac[8]); ac[9] = fmaf(ao, f1, ac[9]); ac[10] = fmaf(ao, f2, ac[10]); ac[11] = fmaf(ao, f3, ac[11]);
    }
#pragma unroll
    for (int w = 0; w < 3; ++w)
      ((uint2*)(priv + PM2 + w * 1024))[tid] =
          make_uint2(bfp(ac[w * 4 + 0], ac[w * 4 + 1]), bfp(ac[w * 4 + 2], ac[w * 4 + 3]));
#pragma unroll
    for (int j = 0; j < 12; ++j) ac[j] = 0.f;
    wsrc = (const uint2*)w2bf;
#pragma unroll 4
    for (int k = 0; k < 1024; ++k) {
      uint2 wp = wsrc[k * 256 + tid];
      float f0 = blo(wp.x), f1 = bhi(wp.x), f2 = blo(wp.y), f3 = bhi(wp.y);
      float ai = arow[3][k], ag = arow[4][k], ao = arow[5][k];
      ac[0] = fmaf(ai, f0, ac[0]); ac[1] = fmaf(ai, f1, ac[1]); ac[2] = fmaf(ai, f2, ac[2]); ac[3] = fmaf(ai, f3, ac[3]);
      ac[4] = fmaf(ag, f0, ac[4]); ac[5] = fmaf(ag, f1, ac[5]); ac[6] = fmaf(ag, f2, ac[6]); ac[7] = fmaf(ag, f3, ac[7]);
      ac[8] = fmaf(ao, f0, ac[8]); ac[9] = fmaf(ao, f1, ac[9]); ac[10] = fmaf(ao, f2, ac[10]); ac[11] = fmaf(ao, f3, ac[11]);
    }
#pragma unroll
    for (int w = 0; w < 3; ++w)
      ((uint2*)(priv + PM3 + w * 1024))[tid] =
          make_uint2(bfp(ac[w * 4 + 0], ac[w * 4 + 1]), bfp(ac[w * 4 + 2], ac[w * 4 + 3]));
  }
  __syncthreads();
  if (tid == 0) sti(iws + SS * b, 2);        // arrive(2): init publishes + GEMM done

  // ======== waves 1..3 are prologue-only; wave 0 runs the recurrent loop solo
  if (wv != 0) return;

  float c1g[3], c2g[3], c3g[3];
#pragma unroll
  for (int g = 0; g < 3; ++g) { c1g[g] = cs1[g]; c2g[g] = cs2[g]; c3g[g] = cs3[g]; }
  const float v1bg = hasV1 ? V1b[b] : 0.f;
  const float v2bg = V2b[b];
  const float v3bg = V3b[b];

  const uint4* pm2  = (const uint4*)(priv + PM2);
  const uint4* pm3  = (const uint4*)(priv + PM3);
  const uint4* pw1r = (const uint4*)(priv + PW1R);
  const uint4* pw2r = (const uint4*)(priv + PW2R);
  const uint4* pv2  = (const uint4*)(priv + PV2);
  const uint4* pv3  = (const uint4*)(priv + PV3);
  const uint4* pv1  = (const uint4*)(priv + PV1);
  const float* a0p  = (const float*)(priv + PA0);
  int* myarr = iws + SS * b;

  for (int t = 0; t < TT; ++t) {
    const int par = t & 1;
    const float* dtd1c = fws + FTD1 + par * 1024;
    float* dtd1n = fws + FTD1 + (par ^ 1) * 1024;
    const float* dtd2o = fws + FTD2 + (par ^ 1) * 1024;
    float* dtd2c = fws + FTD2 + par * 1024;

    // ---- pre-X: W2R @ TD2_{t-1} (certified at flag 1+2t, already passed; zero at t=0)
    float pp0 = 0.f, pp1 = 0.f, pp2 = 0.f;
    if (t > 0) {
      float4 o0 = cld4(dtd2o + 16 * lane),     o1 = cld4(dtd2o + 16 * lane + 4),
             o2 = cld4(dtd2o + 16 * lane + 8), o3 = cld4(dtd2o + 16 * lane + 12);
      pp0 = DOT16(pw2r, 0,   o0, o1, o2, o3);
      pp1 = DOT16(pw2r, 128, o0, o1, o2, o3);
      pp2 = DOT16(pw2r, 256, o0, o1, o2, o3);
    }
    sflag(iws, fl, 2 + 2 * t);

    // ---- X_t: s2 = act(M2@TD1_t + W2R@TD2_{t-1} + c2); TD2_t; rc1_t
    float4 v0 = cld4(dtd1c + 16 * lane),     v1 = cld4(dtd1c + 16 * lane + 4),
           v2 = cld4(dtd1c + 16 * lane + 8), v3 = cld4(dtd1c + 16 * lane + 12);
    {
      float xv3 = 0.f;
      if (t > 0) {
        float4 s0 = cld4(fws + FS3 + 16 * lane),      s1_ = cld4(fws + FS3 + 16 * lane + 4),
               s2_ = cld4(fws + FS3 + 16 * lane + 8), s3_ = cld4(fws + FS3 + 16 * lane + 12);
        xv3 = DOT16(pv3, 0, s0, s1_, s2_, s3_);
      }
      float xv1 = 0.f;
      if (hasV1) {
        float4 u0 = cld4(fws + FS1 + 16 * lane),      u1 = cld4(fws + FS1 + 16 * lane + 4),
               u2 = cld4(fws + FS1 + 16 * lane + 8),  u3 = cld4(fws + FS1 + 16 * lane + 12);
        xv1 = DOT16(pv1, 0, u0, u1, u2, u3);
      }
      float xz0 = DOT16(pm2, 0,   v0, v1, v2, v3);
      float xz1 = DOT16(pm2, 128, v0, v1, v2, v3);
      float xz2 = DOT16(pm2, 256, v0, v1, v2, v3);
      float s2v = sigm(xz2 + pp2 + c2g[2]) *
                  ftanh(sigm(xz0 + pp0 + c2g[0]) * ftanh(xz1 + pp1 + c2g[1]));
      float rc3v = (t == 0) ? 0.f : (xv3 + v3bg);
      if (lane == 0) {
        cst1(fws + FS2 + b, s2v);
        cst1(dtd2c + b, s2v - rc3v);
        if (hasV1) cst1(fws + FRC1 + b, xv1 + v1bg);
        relst(myarr, 3 + 2 * t);             // release: publishes ordered before arrive
      }
      if (b == 0)
        l1 += wredsum(asum4(v0) + asum4(v1) + asum4(v2) + asum4(v3));
    }

    // ---- pre-Y: W1R @ TD1_t (register copy; overlaps the flag wait)
    float py0 = DOT16(pw1r, 0,   v0, v1, v2, v3);
    float py1 = DOT16(pw1r, 128, v0, v1, v2, v3);
    float py2 = DOT16(pw1r, 256, v0, v1, v2, v3);
    sflag(iws, fl, 3 + 2 * t);

    // ---- Y_t: s3_t = act(M3@TD2_t + c3); s1_{t+1} = act(A0@nTD0_{t+1} + W1R@TD1_t + c1);
    //           TD1_{t+1} = s1_{t+1} - (V2@s2_t + v2b)
    {
      float4 d0 = cld4(dtd2c + 16 * lane),     d1 = cld4(dtd2c + 16 * lane + 4),
             d2 = cld4(dtd2c + 16 * lane + 8), d3 = cld4(dtd2c + 16 * lane + 12);
      float4 e0 = cld4(fws + FS2 + 16 * lane),     e1 = cld4(fws + FS2 + 16 * lane + 4),
             e2 = cld4(fws + FS2 + 16 * lane + 8), e3 = cld4(fws + FS2 + 16 * lane + 12);
      float yz0 = DOT16(pm3, 0,   d0, d1, d2, d3);
      float yz1 = DOT16(pm3, 128, d0, d1, d2, d3);
      float yz2 = DOT16(pm3, 256, d0, d1, d2, d3);
      float yv2 = DOT16(pv2, 0, e0, e1, e2, e3);
      const int tn = (t < TT - 1) ? (t + 1) : (TT - 1);
      float nd = 0.f;
      if (lane < CC) nd = inp[tn * CC + lane] - cld1(fws + FRC1 + lane);
      float pa0v = wredsum((lane < CC) ? a0p[lane] * nd : 0.f);
      float pa1v = wredsum((lane < CC) ? a0p[CC + lane] * nd : 0.f);
      float pa2v = wredsum((lane < CC) ? a0p[2 * CC + lane] * nd : 0.f);
      float s3v = sigm(yz2 + c3g[2]) * ftanh(sigm(yz0 + c3g[0]) * ftanh(yz1 + c3g[1]));
      float rc2v = yv2 + v2bg;
      float s1n = sigm(pa2v + py2 + c1g[2]) *
                  ftanh(sigm(pa0v + py0 + c1g[0]) * ftanh(pa1v + py1 + c1g[1]));
      if (lane == 0) {
        cst1(fws + FS3 + b, s3v);
        cst1(fws + FS1 + b, s1n);
        cst1(dtd1n + b, s1n - rc2v);
        relst(myarr, 4 + 2 * t);
      }
      if (b == 0) {
        l2 += wredsum(asum4(d0) + asum4(d1) + asum4(d2) + asum4(d3));
        if (t < TT - 1) l0 += wredsum((lane < CC) ? fabsf(nd) : 0.f);
      }
    }
  }

  if (b == 0 && lane == 0) out[0] = l0 + lam * l1 + lam2 * l2;
}

extern "C" void kernel_launch(void* const* d_in, const int* in_sizes, int n_in,
                              void* d_out, int out_size, void* d_ws, size_t ws_size,
                              hipStream_t stream) {
  const float* inp = (const float*)d_in[0];
  const float* W0w = (const float*)d_in[1];
  const float* W0b = (const float*)d_in[2];
  const float* W1w = (const float*)d_in[3];
  const float* W1b = (const float*)d_in[4];
  const float* W2w = (const float*)d_in[5];
  const float* W2b = (const float*)d_in[6];
  const float* Wi1 = (const float*)d_in[7];
  const float* b1  = (const float*)d_in[8];
  const float* Wi2 = (const float*)d_in[9];
  const float* b2  = (const float*)d_in[10];
  const float* Wi3 = (const float*)d_in[11];
  const float* b3  = (const float*)d_in[12];
  const float* V1w = (const float*)d_in[13];
  const float* V1b = (const float*)d_in[14];
  const float* V2w = (const float*)d_in[15];
  const float* V2b = (const float*)d_in[16];
  const float* V3w = (const float*)d_in[17];
  const float* V3b = (const float*)d_in[18];
  const int*   itn = (const int*)d_in[19];

  hipLaunchKernelGGL(predcells, dim3(GRID + 1), dim3(NT), 0, stream,
                     inp, W0w, W0b, W1w, W1b, W2w, W2b,
                     Wi1, b1, Wi2, b2, Wi3, b3,
                     V1w, V1b, V2w, V2b, V3w, V3b, itn,
                     (float*)d_out, (char*)d_ws);
}

// Round 6
// 1206.858 us; speedup vs baseline: 98.1021x; 98.1021x over previous
//
#include <hip/hip_runtime.h>

#define CC 56
#define TT 64
#define GRID 1024
#define NT 256
#define NFLAG 64
#define SS 32                    // 128 B stride between sync slots
#define FB (GRID * SS)           // flag base (int index)
#define AGENT __HIP_MEMORY_SCOPE_AGENT

// ---- ws byte offsets
#define OFF_FWS   147456         // carry vectors (floats)
#define OFF_W1BF  262144         // W1 bf16, 2 MB
#define OFF_W2BF  2359296       // W2 bf16, 2 MB
#define OFF_PRIV  4456448       // 1024 × 32 KB private regions
#define PRIVB     32768

// ---- private region offsets (ushort units)
#define PM2  0                   // M2 rows (i,g,o) 3×1024 bf16
#define PM3  3072
#define PW1R 6144                // Wi1 right-half rows
#define PW2R 9216                // Wi2 right-half rows
#define PV2  12288
#define PV3  13312
#define PV1  14336
#define PA0  15360               // A0 fp32 3×56 at byte 30720

// ---- fws float offsets (all coherent)
#define FS1   0
#define FS2   1024
#define FS3   2048
#define FTD1  3072               // two parity slots 3072/4096
#define FTD2  5120               // two parity slots 5120/6144
#define FRC1  7168               // 64

static __device__ __forceinline__ float wredsum(float v) {
#pragma unroll
  for (int m = 32; m; m >>= 1) v += __shfl_xor(v, m, 64);
  return v;
}
static __device__ __forceinline__ float sigm(float x) { return 1.f / (1.f + __expf(-x)); }
static __device__ __forceinline__ float ftanh(float x) {
  x = fminf(15.f, fmaxf(-15.f, x));
  float e = __expf(2.f * x);
  return (e - 1.f) / (e + 1.f);
}

// coherent accessors (agent-scope) for repeatedly-rewritten data
static __device__ __forceinline__ float2 cld2(const float* p) {
  unsigned long long u = __hip_atomic_load((const unsigned long long*)p, __ATOMIC_RELAXED, AGENT);
  union { unsigned long long u; float2 f; } c; c.u = u; return c.f;
}
static __device__ __forceinline__ float4 cld4(const float* p) {
  float2 a = cld2(p), b = cld2(p + 2);
  return make_float4(a.x, a.y, b.x, b.y);
}
static __device__ __forceinline__ float cld1(const float* p) {
  return __uint_as_float(__hip_atomic_load((const unsigned int*)p, __ATOMIC_RELAXED, AGENT));
}
static __device__ __forceinline__ void cst1(float* p, float v) {
  __hip_atomic_store((unsigned int*)p, __float_as_uint(v), __ATOMIC_RELAXED, AGENT);
}
static __device__ __forceinline__ void cstu2(unsigned* p, unsigned a, unsigned b) {
  unsigned long long u = (unsigned long long)a | ((unsigned long long)b << 32);
  __hip_atomic_store((unsigned long long*)p, u, __ATOMIC_RELAXED, AGENT);
}
static __device__ __forceinline__ int ldi(const int* p) {
  return __hip_atomic_load(p, __ATOMIC_RELAXED, AGENT);
}
static __device__ __forceinline__ void sti(int* p, int v) {
  __hip_atomic_store(p, v, __ATOMIC_RELAXED, AGENT);
}

// bf16 pack (RNE) + dot helpers
static __device__ __forceinline__ unsigned bfp(float lo, float hi) {
  unsigned a = __float_as_uint(lo), b = __float_as_uint(hi);
  a = (a + 0x7fffu + ((a >> 16) & 1u)) >> 16;
  b = (b + 0x7fffu + ((b >> 16) & 1u)) >> 16;
  return a | (b << 16);
}
static __device__ __forceinline__ float blo(unsigned u) { return __uint_as_float(u << 16); }
static __device__ __forceinline__ float bhi(unsigned u) { return __uint_as_float(u & 0xffff0000u); }
static __device__ __forceinline__ float bdot2(uint2 w, float4 v) {
  float r = blo(w.x) * v.x;
  r = fmaf(bhi(w.x), v.y, r);
  r = fmaf(blo(w.y), v.z, r);
  r = fmaf(bhi(w.y), v.w, r);
  return r;
}
static __device__ __forceinline__ float asum4(float4 v) {
  return fabsf(v.x) + fabsf(v.y) + fabsf(v.z) + fabsf(v.w);
}

// master-relay barrier (verified, identical topology to the 1021 µs baseline)
static __device__ __forceinline__ void warr(int* iws, int g, int b) {
  __syncthreads();
  if (threadIdx.x == 0) sti(iws + SS * b, g);
}
static __device__ __forceinline__ void wwait(int* iws, int g, int b) {
  if (b == 0) {
    const int* p0 = iws + SS * threadIdx.x;
    for (;;) {
      int a0 = ldi(p0), a1 = ldi(p0 + SS * 256), a2 = ldi(p0 + SS * 512), a3 = ldi(p0 + SS * 768);
      if (a0 >= g && a1 >= g && a2 >= g && a3 >= g) break;
      __builtin_amdgcn_s_sleep(1);
    }
    __syncthreads();
    if (threadIdx.x < NFLAG) sti(iws + FB + SS * threadIdx.x, g);
  } else {
    if (threadIdx.x == 0)
      while (ldi(iws + FB + SS * (b & (NFLAG - 1))) < g) __builtin_amdgcn_s_sleep(1);
  }
  __asm__ __volatile__("" ::: "memory");
  __syncthreads();
}

// 1024-dot: wave-local, 16 fp32/lane (used for prologue constants)
static __device__ __forceinline__ float dotw(const float* a, const float* c, int lane) {
  const float4* a4 = (const float4*)a;
  const float4* c4 = (const float4*)c;
  float acc = 0.f;
#pragma unroll
  for (int j = 0; j < 4; ++j) {
    float4 x = a4[lane * 4 + j], y = c4[lane * 4 + j];
    acc = fmaf(x.x, y.x, fmaf(x.y, y.y, fmaf(x.z, y.z, fmaf(x.w, y.w, acc))));
  }
  return wredsum(acc);
}

__global__ void __launch_bounds__(NT, 4) predcells(
    const float* __restrict__ inp,
    const float* __restrict__ W0w, const float* __restrict__ W0b,
    const float* __restrict__ W1w, const float* __restrict__ W1b,
    const float* __restrict__ W2w, const float* __restrict__ W2b,
    const float* __restrict__ Wi1, const float* __restrict__ b1,
    const float* __restrict__ Wi2, const float* __restrict__ b2,
    const float* __restrict__ Wi3, const float* __restrict__ b3,
    const float* __restrict__ V1w, const float* __restrict__ V1b,
    const float* __restrict__ V2w, const float* __restrict__ V2b,
    const float* __restrict__ V3w, const float* __restrict__ V3b,
    const int* __restrict__ itn,
    float* __restrict__ out, char* ws)
{
  const int tid = threadIdx.x;
  const int lane = tid & 63;
  const int wv = tid >> 6;
  const int b = blockIdx.x;
  const bool hasV1 = (b < CC);

  int* iws = (int*)ws;
  float* fws = (float*)(ws + OFF_FWS);
  unsigned short* w1bf = (unsigned short*)(ws + OFF_W1BF);
  unsigned short* w2bf = (unsigned short*)(ws + OFF_W2BF);
  unsigned short* priv = (unsigned short*)(ws + OFF_PRIV + (size_t)b * PRIVB);

  __shared__ float arow[6][1024];           // GEMM staging (24 KB)
  __shared__ float psX[6][4], psP[3][4], psA[3];
  __shared__ float cs1[3], cs2[3], cs3[3];

  const int gofs = (wv == 0) ? 0 : ((wv == 1) ? 2048 : 3072);  // i,g,o rows for waves 0..2

  // ======== phase 0: convert W1/W2 row b to shared bf16 (coherent stores)
  {
    float4 r1 = ((const float4*)(W1w + (size_t)b * 1024))[tid];
    cstu2((unsigned*)(w1bf + (size_t)b * 1024 + 4 * tid), bfp(r1.x, r1.y), bfp(r1.z, r1.w));
    float4 r2 = ((const float4*)(W2w + (size_t)b * 1024))[tid];
    cstu2((unsigned*)(w2bf + (size_t)b * 1024 + 4 * tid), bfp(r2.x, r2.y), bfp(r2.z, r2.w));
  }
  warr(iws, 1, b);

  // ======== phase 1 (during barrier-1 window): local prep
  const float lam = (itn[0] <= 1000) ? 1e-4f : 1e-2f;
  const float lam2 = lam * lam;
  const float v1b_b = hasV1 ? V1b[b] : 0.f;
  const float v2b_b = V2b[b];
  const float v3b_b = V3b[b];
  float l0 = 0.f, l1 = 0.f, l2 = 0.f;  // loss partials — BLOCK 1 (master stays lean)

  if (wv < 3) {
    float c1v = b1[b + gofs] + dotw(Wi1 + (size_t)(b + gofs) * 2048, W0b, lane);
    float c2v = b2[b + gofs] + dotw(Wi2 + (size_t)(b + gofs) * 2048, W1b, lane);
    float c3v = b3[b + gofs] + dotw(Wi3 + (size_t)(b + gofs) * 1024, W2b, lane);
    if (lane == 0) { cs1[wv] = c1v; cs2[wv] = c2v; cs3[wv] = c3v; }
    if (lane < CC) {
      const float* wr = Wi1 + (size_t)(b + gofs) * 2048;
      float acc = 0.f;
      for (int k = 0; k < 1024; ++k) acc = fmaf(wr[k], W0w[k * CC + lane], acc);
      ((float*)(priv + PA0))[wv * CC + lane] = acc;
    }
    {
      float4 x = ((const float4*)(Wi1 + (size_t)(b + gofs) * 2048 + 1024))[lane];
      ((uint2*)(priv + PW1R + wv * 1024))[lane] = make_uint2(bfp(x.x, x.y), bfp(x.z, x.w));
      float4 y = ((const float4*)(Wi2 + (size_t)(b + gofs) * 2048 + 1024))[lane];
      ((uint2*)(priv + PW2R + wv * 1024))[lane] = make_uint2(bfp(y.x, y.y), bfp(y.z, y.w));
    }
  } else {
#pragma unroll
    for (int j = 0; j < 4; ++j) {
      int i = lane * 4 + j;
      float4 a = ((const float4*)(V2w + (size_t)b * 1024))[i];
      ((uint2*)(priv + PV2))[i] = make_uint2(bfp(a.x, a.y), bfp(a.z, a.w));
      float4 c = ((const float4*)(V3w + (size_t)b * 1024))[i];
      ((uint2*)(priv + PV3))[i] = make_uint2(bfp(c.x, c.y), bfp(c.z, c.w));
      if (hasV1) {
        float4 d = ((const float4*)(V1w + (size_t)b * 1024))[i];
        ((uint2*)(priv + PV1))[i] = make_uint2(bfp(d.x, d.y), bfp(d.z, d.w));
      }
    }
  }
  __syncthreads();
  if (wv < 3) {
    float p = 0.f, ax = 0.f;
    if (lane < CC) {
      float xv = inp[lane];
      p = ((const float*)(priv + PA0))[wv * CC + lane] * xv;
      ax = fabsf(xv);
    }
    p = wredsum(p);
    ax = wredsum(ax);
    if (lane == 0) psA[wv] = p;
    if (b == 1 && wv == 0) l0 += ax;   // |nTD0_0|
  }
  __syncthreads();
  if (tid == 0) {
    float s1v = sigm(psA[2] + cs1[2]) * ftanh(sigm(psA[0] + cs1[0]) * ftanh(psA[1] + cs1[1]));
    cst1(fws + FS1 + b, s1v);
    cst1(fws + FTD1 + b, s1v);        // parity 0
    cst1(fws + FS3 + b, 0.f);
    cst1(fws + FTD2 + 1024 + b, 0.f); // parity 1
  }
  wwait(iws, 1, b);

  // ======== phase 2: GEMMs M2 = Wi2_L@W1, M3 = Wi3@W2 → private bf16
  {
#pragma unroll
    for (int w = 0; w < 3; ++w) {
      int go = (w == 0) ? 0 : ((w == 1) ? 2048 : 3072);
      ((float4*)arow[w])[tid]     = ((const float4*)(Wi2 + (size_t)(b + go) * 2048))[tid];
      ((float4*)arow[3 + w])[tid] = ((const float4*)(Wi3 + (size_t)(b + go) * 1024))[tid];
    }
    __syncthreads();
    float ac[12];
#pragma unroll
    for (int j = 0; j < 12; ++j) ac[j] = 0.f;
    const uint2* wsrc = (const uint2*)w1bf;
#pragma unroll 4
    for (int k = 0; k < 1024; ++k) {
      uint2 wp = wsrc[k * 256 + tid];
      float f0 = blo(wp.x), f1 = bhi(wp.x), f2 = blo(wp.y), f3 = bhi(wp.y);
      float ai = arow[0][k], ag = arow[1][k], ao = arow[2][k];
      ac[0] = fmaf(ai, f0, ac[0]); ac[1] = fmaf(ai, f1, ac[1]); ac[2] = fmaf(ai, f2, ac[2]); ac[3] = fmaf(ai, f3, ac[3]);
      ac[4] = fmaf(ag, f0, ac[4]); ac[5] = fmaf(ag, f1, ac[5]); ac[6] = fmaf(ag, f2, ac[6]); ac[7] = fmaf(ag, f3, ac[7]);
      ac[8] = fmaf(ao, f0, ac[8]); ac[9] = fmaf(ao, f1, ac[9]); ac[10] = fmaf(ao, f2, ac[10]); ac[11] = fmaf(ao, f3, ac[11]);
    }
#pragma unroll
    for (int w = 0; w < 3; ++w)
      ((uint2*)(priv + PM2 + w * 1024))[tid] =
          make_uint2(bfp(ac[w * 4 + 0], ac[w * 4 + 1]), bfp(ac[w * 4 + 2], ac[w * 4 + 3]));
#pragma unroll
    for (int j = 0; j < 12; ++j) ac[j] = 0.f;
    wsrc = (const uint2*)w2bf;
#pragma unroll 4
    for (int k = 0; k < 1024; ++k) {
      uint2 wp = wsrc[k * 256 + tid];
      float f0 = blo(wp.x), f1 = bhi(wp.x), f2 = blo(wp.y), f3 = bhi(wp.y);
      float ai = arow[3][k], ag = arow[4][k], ao = arow[5][k];
      ac[0] = fmaf(ai, f0, ac[0]); ac[1] = fmaf(ai, f1, ac[1]); ac[2] = fmaf(ai, f2, ac[2]); ac[3] = fmaf(ai, f3, ac[3]);
      ac[4] = fmaf(ag, f0, ac[4]); ac[5] = fmaf(ag, f1, ac[5]); ac[6] = fmaf(ag, f2, ac[6]); ac[7] = fmaf(ag, f3, ac[7]);
      ac[8] = fmaf(ao, f0, ac[8]); ac[9] = fmaf(ao, f1, ac[9]); ac[10] = fmaf(ao, f2, ac[10]); ac[11] = fmaf(ao, f3, ac[11]);
    }
#pragma unroll
    for (int w = 0; w < 3; ++w)
      ((uint2*)(priv + PM3 + w * 1024))[tid] =
          make_uint2(bfp(ac[w * 4 + 0], ac[w * 4 + 1]), bfp(ac[w * 4 + 2], ac[w * 4 + 3]));
  }
  warr(iws, 2, b);

  // ======== recurrent loop: 2 barriers/step; loads-first reorder hides L3 RTT under pre-dots
  int g = 2;
  const uint2* pm2 = (const uint2*)(priv + PM2);
  const uint2* pm3 = (const uint2*)(priv + PM3);
  const uint2* pw1r = (const uint2*)(priv + PW1R);
  const uint2* pw2r = (const uint2*)(priv + PW2R);
  const uint2* pv2 = (const uint2*)(priv + PV2);
  const uint2* pv3 = (const uint2*)(priv + PV3);
  const uint2* pv1 = (const uint2*)(priv + PV1);
  const float* a0p = (const float*)(priv + PA0);

  float4 vtd1 = make_float4(0.f, 0.f, 0.f, 0.f);

  for (int t = 0; t < TT; ++t) {
    const int par = t & 1;
    float* td1cur = fws + FTD1 + par * 1024;
    float* td1nxt = fws + FTD1 + (par ^ 1) * 1024;
    float* td2old = fws + FTD2 + (par ^ 1) * 1024;
    float* td2cur = fws + FTD2 + par * 1024;

    // TD2_{t-1}: parity-stable, certified two flags ago — load before the wait
    float4 ov = make_float4(0.f, 0.f, 0.f, 0.f);
    if (t > 0) ov = cld4(td2old + 4 * tid);

    wwait(iws, g, b);

    // ---- X_t (merged pre-X): issue certified loads first, pre-dots in their shadow
    {
      vtd1 = cld4(td1cur + 4 * tid);
      float4 vs3 = make_float4(0.f, 0.f, 0.f, 0.f);
      if (t > 0) vs3 = cld4(fws + FS3 + 4 * tid);
      float4 vs1 = make_float4(0.f, 0.f, 0.f, 0.f);
      if (hasV1) vs1 = cld4(fws + FS1 + 4 * tid);

      float q0 = 0.f, q1 = 0.f, q2 = 0.f;
      if (t > 0) {
        uint2 wr0 = pw2r[tid], wr1 = pw2r[256 + tid], wr2 = pw2r[512 + tid];
        q0 = wredsum(bdot2(wr0, ov));
        q1 = wredsum(bdot2(wr1, ov));
        q2 = wredsum(bdot2(wr2, ov));
      }
      if (lane == 0) { psP[0][wv] = q0; psP[1][wv] = q1; psP[2][wv] = q2; }

      uint2 wm0 = pm2[tid], wm1 = pm2[256 + tid], wm2v = pm2[512 + tid];
      float p0 = wredsum(bdot2(wm0, vtd1));
      float p1 = wredsum(bdot2(wm1, vtd1));
      float p2 = wredsum(bdot2(wm2v, vtd1));
      float p3 = 0.f;
      if (t > 0) { uint2 w3 = pv3[tid]; p3 = wredsum(bdot2(w3, vs3)); }
      if (lane == 0) { psX[0][wv] = p0; psX[1][wv] = p1; psX[2][wv] = p2; psX[3][wv] = p3; }
      if (hasV1) {
        uint2 w1 = pv1[tid];
        float pv = wredsum(bdot2(w1, vs1));
        if (lane == 0) psX[4][wv] = pv;
      }
      if (b == 1) {
        float al = wredsum(asum4(vtd1));
        if (lane == 0) psX[5][wv] = al;
      }
      __syncthreads();
      if (tid == 0) {
        float zi = psX[0][0] + psX[0][1] + psX[0][2] + psX[0][3] + psP[0][0] + psP[0][1] + psP[0][2] + psP[0][3] + cs2[0];
        float zg = psX[1][0] + psX[1][1] + psX[1][2] + psX[1][3] + psP[1][0] + psP[1][1] + psP[1][2] + psP[1][3] + cs2[1];
        float zo = psX[2][0] + psX[2][1] + psX[2][2] + psX[2][3] + psP[2][0] + psP[2][1] + psP[2][2] + psP[2][3] + cs2[2];
        float s2v = sigm(zo) * ftanh(sigm(zi) * ftanh(zg));
        float rc3v = (t == 0) ? 0.f : (psX[3][0] + psX[3][1] + psX[3][2] + psX[3][3] + v3b_b);
        cst1(fws + FS2 + b, s2v);
        cst1(td2cur + b, s2v - rc3v);
        if (hasV1) cst1(fws + FRC1 + b, psX[4][0] + psX[4][1] + psX[4][2] + psX[4][3] + v1b_b);
        if (b == 1) l1 += psX[5][0] + psX[5][1] + psX[5][2] + psX[5][3];
      }
    }
    warr(iws, ++g, b);

    wwait(iws, g, b);
    // ---- Y_t (merged pre-Y): issue certified loads first, pre-Y dots on register vtd1
    {
      float4 vtd2 = cld4(td2cur + 4 * tid);
      float4 vs2  = cld4(fws + FS2 + 4 * tid);
      float rcv = 0.f;
      if (wv < 3 && lane < CC) rcv = cld1(fws + FRC1 + lane);

      {
        uint2 wr0 = pw1r[tid], wr1 = pw1r[256 + tid], wr2 = pw1r[512 + tid];
        float q0 = wredsum(bdot2(wr0, vtd1));
        float q1 = wredsum(bdot2(wr1, vtd1));
        float q2 = wredsum(bdot2(wr2, vtd1));
        if (lane == 0) { psP[0][wv] = q0; psP[1][wv] = q1; psP[2][wv] = q2; }
      }

      uint2 wm0 = pm3[tid], wm1 = pm3[256 + tid], wm2v = pm3[512 + tid];
      uint2 w2 = pv2[tid];
      float p0 = wredsum(bdot2(wm0, vtd2));
      float p1 = wredsum(bdot2(wm1, vtd2));
      float p2 = wredsum(bdot2(wm2v, vtd2));
      float p3 = wredsum(bdot2(w2, vs2));
      if (lane == 0) { psX[0][wv] = p0; psX[1][wv] = p1; psX[2][wv] = p2; psX[3][wv] = p3; }
      if (b == 1) {
        float al = wredsum(asum4(vtd2));
        if (lane == 0) psX[5][wv] = al;
      }
      if (wv < 3) {
        const int tn = (t < TT - 1) ? (t + 1) : (TT - 1);
        float p = 0.f, ax = 0.f;
        if (lane < CC) {
          float xv = inp[tn * CC + lane];
          float ndv = xv - rcv;
          p = a0p[wv * CC + lane] * ndv;
          ax = fabsf(ndv);
        }
        p = wredsum(p);
        ax = wredsum(ax);
        if (lane == 0) psA[wv] = p;
        if (b == 1 && wv == 0 && t < TT - 1) l0 += ax;
      }
      __syncthreads();
      if (tid == 0) {
        float z3i = psX[0][0] + psX[0][1] + psX[0][2] + psX[0][3] + cs3[0];
        float z3g = psX[1][0] + psX[1][1] + psX[1][2] + psX[1][3] + cs3[1];
        float z3o = psX[2][0] + psX[2][1] + psX[2][2] + psX[2][3] + cs3[2];
        cst1(fws + FS3 + b, sigm(z3o) * ftanh(sigm(z3i) * ftanh(z3g)));
        float rc2v = psX[3][0] + psX[3][1] + psX[3][2] + psX[3][3] + v2b_b;
        float z1i = psA[0] + psP[0][0] + psP[0][1] + psP[0][2] + psP[0][3] + cs1[0];
        float z1g = psA[1] + psP[1][0] + psP[1][1] + psP[1][2] + psP[1][3] + cs1[1];
        float z1o = psA[2] + psP[2][0] + psP[2][1] + psP[2][2] + psP[2][3] + cs1[2];
        float s1n = sigm(z1o) * ftanh(sigm(z1i) * ftanh(z1g));
        cst1(fws + FS1 + b, s1n);
        cst1(td1nxt + b, s1n - rc2v);
        if (b == 1) l2 += psX[5][0] + psX[5][1] + psX[5][2] + psX[5][3];
      }
    }
    warr(iws, ++g, b);
  }

  if (b == 1 && tid == 0) out[0] = l0 + lam * l1 + lam2 * l2;
}

extern "C" void kernel_launch(void* const* d_in, const int* in_sizes, int n_in,
                              void* d_out, int out_size, void* d_ws, size_t ws_size,
                              hipStream_t stream) {
  const float* inp = (const float*)d_in[0];
  const float* W0w = (const float*)d_in[1];
  const float* W0b = (const float*)d_in[2];
  const float* W1w = (const float*)d_in[3];
  const float* W1b = (const float*)d_in[4];
  const float* W2w = (const float*)d_in[5];
  const float* W2b = (const float*)d_in[6];
  const float* Wi1 = (const float*)d_in[7];
  const float* b1  = (const float*)d_in[8];
  const float* Wi2 = (const float*)d_in[9];
  const float* b2  = (const float*)d_in[10];
  const float* Wi3 = (const float*)d_in[11];
  const float* b3  = (const float*)d_in[12];
  const float* V1w = (const float*)d_in[13];
  const float* V1b = (const float*)d_in[14];
  const float* V2w = (const float*)d_in[15];
  const float* V2b = (const float*)d_in[16];
  const float* V3w = (const float*)d_in[17];
  const float* V3b = (const float*)d_in[18];
  const int*   itn = (const int*)d_in[19];

  hipLaunchKernelGGL(predcells, dim3(GRID), dim3(NT), 0, stream,
                     inp, W0w, W0b, W1w, W1b, W2w, W2b,
                     Wi1, b1, Wi2, b2, Wi3, b3,
                     V1w, V1b, V2w, V2b, V3w, V3b, itn,
                     (float*)d_out, (char*)d_ws);
}